// Round 16
// baseline (411.096 us; speedup 1.0000x reference)
//
#include <hip/hip_runtime.h>
#include <hip/hip_bf16.h>
#include <cstdint>
#include <cstddef>

// B=2, S=2048, D=1024, R=64, H=16, DH=64, N=32; BS=4096
typedef unsigned short u16;
typedef short bfrag __attribute__((ext_vector_type(8)));      // 8 bf16
typedef _Float16 hfrag __attribute__((ext_vector_type(8)));   // 8 fp16
typedef float f32x4 __attribute__((ext_vector_type(4)));
typedef u16 u16x8 __attribute__((ext_vector_type(8)));

__device__ __forceinline__ u16 f2bf(float v) {
    union { float f; unsigned u; } a; a.f = v;
    unsigned r = a.u + 0x7fff + ((a.u >> 16) & 1);   // RNE
    return (u16)(r >> 16);
}
__device__ __forceinline__ float bf2f(u16 u) {
    union { unsigned u; float f; } a; a.u = ((unsigned)u) << 16;
    return a.f;
}
__device__ __forceinline__ u16 f2h(float v) {
    union { _Float16 h; u16 u; } a; a.h = (_Float16)v;
    return a.u;
}
__device__ __forceinline__ f32x4 mfma_bf16(bfrag a, bfrag b, f32x4 c) {
    return __builtin_amdgcn_mfma_f32_16x16x32_bf16(a, b, c, 0, 0, 0);
}
__device__ __forceinline__ f32x4 mfma_f16(hfrag a, hfrag b, f32x4 c) {
    return __builtin_amdgcn_mfma_f32_16x16x32_f16(a, b, c, 0, 0, 0);
}
__device__ __forceinline__ void async_copy16(const void* g, void* l) {
    __builtin_amdgcn_global_load_lds(
        (const __attribute__((address_space(1))) unsigned*)g,
        (__attribute__((address_space(3))) unsigned*)l, 16, 0, 0);
}
__device__ __forceinline__ int get_xcd() {
    unsigned x;
    asm volatile("s_getreg_b32 %0, hwreg(HW_REG_XCC_ID)" : "=s"(x));
    return (int)(x & 7);
}

// ---------------------------------------------------------------------------
// elementwise cast fp32 -> bf16 hi (+lo if SPLIT); n4 = count/4
// ---------------------------------------------------------------------------
template<int SPLIT>
__global__ __launch_bounds__(256) void cast_split(const float* __restrict__ s,
                                                  u16* __restrict__ dh,
                                                  u16* __restrict__ dl, int n4)
{
    int i = blockIdx.x * 256 + threadIdx.x;
    if (i >= n4) return;
    float4 v = ((const float4*)s)[i];
    float vv[4] = {v.x, v.y, v.z, v.w};
    ushort4 h, l;
    u16* hp = (u16*)&h; u16* lp = (u16*)&l;
#pragma unroll
    for (int e = 0; e < 4; ++e) {
        u16 hb = f2bf(vv[e]);
        hp[e] = hb;
        if (SPLIT) lp[e] = f2bf(vv[e] - bf2f(hb));
    }
    ((ushort4*)dh)[i] = h;
    if (SPLIT) ((ushort4*)dl)[i] = l;
}

// ---------------------------------------------------------------------------
// transpose + cast: dst[z*C + c][r] = src[z*R*C + r*C + c]; dst pitch dpitch.
// MODE 0: bf16 single; MODE 1: bf16 hi/lo split; MODE 2: fp16 single.
// ---------------------------------------------------------------------------
template<int MODE>
__global__ __launch_bounds__(256) void transpose_cast(const float* __restrict__ src,
                                                      u16* __restrict__ dh,
                                                      u16* __restrict__ dl,
                                                      int R, int C, int dpitch)
{
    __shared__ float t[32][33];
    int z = blockIdx.z;
    const float* s = src + (size_t)z * R * C;
    int r0 = blockIdx.y * 32, c0 = blockIdx.x * 32;
    int tx = threadIdx.x & 31, ty = threadIdx.x >> 5;
#pragma unroll
    for (int p = 0; p < 4; ++p)
        t[ty + p * 8][tx] = s[(size_t)(r0 + ty + p * 8) * C + c0 + tx];
    __syncthreads();
#pragma unroll
    for (int p = 0; p < 4; ++p) {
        int rr = ty + p * 8;
        float v = t[tx][rr];
        size_t di = (size_t)(z * C + c0 + rr) * dpitch + r0 + tx;
        if (MODE == 2) {
            dh[di] = f2h(v);
        } else {
            u16 hb = f2bf(v);
            dh[di] = hb;
            if (MODE == 1) dl[di] = f2bf(v - bf2f(hb));
        }
    }
}

// ---------------------------------------------------------------------------
// merged fp16 transpose for r_qk and r_v (same shape): gridDim.z selects the
// tensor.  Element mapping/rounding identical to transpose_cast<2>.
// ---------------------------------------------------------------------------
__global__ __launch_bounds__(256) void transpose_cast_h2(
    const float* __restrict__ s0, u16* __restrict__ d0,
    const float* __restrict__ s1, u16* __restrict__ d1,
    int R, int C, int dpitch)
{
    __shared__ float t[32][33];
    const float* s = blockIdx.z ? s1 : s0;
    u16* dh        = blockIdx.z ? d1 : d0;
    int r0 = blockIdx.y * 32, c0 = blockIdx.x * 32;
    int tx = threadIdx.x & 31, ty = threadIdx.x >> 5;
#pragma unroll
    for (int p = 0; p < 4; ++p)
        t[ty + p * 8][tx] = s[(size_t)(r0 + ty + p * 8) * C + c0 + tx];
    __syncthreads();
#pragma unroll
    for (int p = 0; p < 4; ++p) {
        int rr = ty + p * 8;
        dh[(size_t)(c0 + rr) * dpitch + r0 + tx] = f2h(t[tx][rr]);
    }
}

// ---------------------------------------------------------------------------
// MFMA bf16 GEMM 128x128, BK=32 (project / outproj).
// XCD-inverted tiling: xq = bid&7 (~XCD under round-robin dispatch) owns
// rowt in [xq*RP, xq*RP+RP) (RP = M/128/8) and iterates ct -> the A row-slice
// stays L2-resident per XCD; B streams via L3 (small footprint).
// Double-buffered LDS, ONE barrier per K-step.
// ---------------------------------------------------------------------------
template<int SPLIT, int CTH>
__global__ __launch_bounds__(256) void gemm_mfma(const u16* __restrict__ Agh,
                                                 const u16* __restrict__ Agl,
                                                 const u16* __restrict__ Bgh,
                                                 const u16* __restrict__ Bgl,
                                                 float* __restrict__ C,
                                                 int M, int N, int K)
{
    constexpr int HB = SPLIT ? 16384 : 8192;   // u16 per LDS buffer
    __shared__ u16 lds[2 * HB];

    const int bid = blockIdx.x;
    const int xq  = bid & 7;
    const int s   = bid >> 3;
    const int RP  = (M >> 7) >> 3;            // rowts per XCD (=4)
    const int rowt = xq * RP + (s % RP);
    const int ct   = s / RP;
    const int row0 = rowt * 128;
    const int col0 = ct * 128;

    const int tid  = threadIdx.x;
    const int lane = tid & 63;
    const int wv   = tid >> 6;
    const int q    = lane >> 4;
    const int tn   = lane & 15;
    const int wm   = (wv >> 1) * 64;
    const int wn   = (wv & 1) * 64;
    const int wbase = (tid & 192) * 8;

    auto stage = [&](u16* base, int k0) {
        u16* Ath = base;
        u16* Atl = SPLIT ? (base + 4096) : base;
        u16* Bth = base + (SPLIT ? 8192 : 4096);
        u16* Btl = SPLIT ? (base + 12288) : base;
#pragma unroll
        for (int shot = 0; shot < 2; ++shot) {
            int G = tid + shot * 256;
            int row = G >> 2, kgs = G & 3;
            int kgg = kgs ^ ((row >> 1) & 3);
            size_t goffB = (size_t)(col0 + row) * K + k0 + kgg * 8;
            async_copy16(Bgh + goffB, Bth + shot * 2048 + wbase);
            if (SPLIT) async_copy16(Bgl + goffB, Btl + shot * 2048 + wbase);
            size_t goffA = (size_t)(row0 + row) * K + k0 + kgg * 8;
            async_copy16(Agh + goffA, Ath + shot * 2048 + wbase);
            if (SPLIT) async_copy16(Agl + goffA, Atl + shot * 2048 + wbase);
        }
    };

    f32x4 acc[4][4];
#pragma unroll
    for (int i = 0; i < 4; ++i)
#pragma unroll
        for (int j = 0; j < 4; ++j) acc[i][j] = 0.f;

    stage(lds, 0);
    __syncthreads();                     // buf0 ready

    int cur = 0;
    const int NT = K >> 5;
    for (int n = 0; n < NT; ++n) {
        if (n + 1 < NT) stage(lds + (cur ^ 1) * HB, (n + 1) * 32);

        const u16* base = lds + cur * HB;
        const u16* Ath = base;
        const u16* Atl = SPLIT ? (base + 4096) : base;
        const u16* Bth = base + (SPLIT ? 8192 : 4096);
        const u16* Btl = SPLIT ? (base + 12288) : base;

        bfrag ah[4], bh[4], al[4], bl[4];
#pragma unroll
        for (int i = 0; i < 4; ++i) {
            int m = wm + i * 16 + tn;
            int g = m * 4 + (q ^ ((m >> 1) & 3));
            ah[i] = *(const bfrag*)(Ath + g * 8);
            if (SPLIT) al[i] = *(const bfrag*)(Atl + g * 8);
        }
#pragma unroll
        for (int j = 0; j < 4; ++j) {
            int n2 = wn + j * 16 + tn;
            int g = n2 * 4 + (q ^ ((n2 >> 1) & 3));
            bh[j] = *(const bfrag*)(Bth + g * 8);
            if (SPLIT) bl[j] = *(const bfrag*)(Btl + g * 8);
        }
#pragma unroll
        for (int i = 0; i < 4; ++i)
#pragma unroll
            for (int j = 0; j < 4; ++j) {
                acc[i][j] = mfma_bf16(ah[i], bh[j], acc[i][j]);
                if (SPLIT) {
                    acc[i][j] = mfma_bf16(ah[i], bl[j], acc[i][j]);
                    acc[i][j] = mfma_bf16(al[i], bh[j], acc[i][j]);
                }
            }
        __syncthreads();
        cur ^= 1;
    }

#pragma unroll
    for (int i = 0; i < 4; ++i)
#pragma unroll
        for (int j = 0; j < 4; ++j)
#pragma unroll
            for (int rg = 0; rg < 4; ++rg) {
                int row = row0 + wm + i * 16 + q * 4 + rg;
                int col = col0 + wn + j * 16 + tn;
                C[(size_t)row * N + col] = acc[i][j][rg];
            }
}

// ---------------------------------------------------------------------------
// Mix: h1[bs,r] = sum_n w1[bs,n] * P[bs, n*64+r]  (optionally h2 with w2)
// (verified original fmaf chain; h consumed in-register by restore_mega)
// ---------------------------------------------------------------------------
__global__ __launch_bounds__(256) void mix_kernel(const float* __restrict__ P,
                                                  const float* __restrict__ w1,
                                                  const float* __restrict__ w2,
                                                  float* __restrict__ h1,
                                                  float* __restrict__ h2,
                                                  int two)
{
    int tid = blockIdx.x * 256 + threadIdx.x;
    int bs = tid >> 6;
    int r  = tid & 63;
    const float* Pp = P + (size_t)bs * 2048 + r;
    float a = 0.f, b = 0.f;
#pragma unroll
    for (int n = 0; n < 32; ++n) {
        float p = Pp[n * 64];
        a = fmaf(w1[bs * 32 + n], p, a);
        if (two) b = fmaf(w2[bs * 32 + n], p, b);
    }
    h1[tid] = a;
    if (two) h2[tid] = b;
}

// ---------------------------------------------------------------------------
// Fused restore GEMMs, fp16, 128x128 tiles, XCD work-queue, 512-thread
// blocks, on-the-fly A (A[m,k] = fp16(h[m,k&63]*wr[m,k>>6]) from
// register-resident h + LDS-splatted wr; single RNE rounding, bit-identical).
// BK=64 B-tiles, DOUBLE-BUFFERED with COUNTED vmcnt (T3+T4): stage(next) is
// issued before compute(cur); s_waitcnt vmcnt(2) waits only cur's 2 loads
// (loads retire in order), RAW s_barrier (no vmcnt(0) drain) -> next-tile
// loads stay in flight across the MFMA phase.  Per-wave count audit:
// prologue __syncthreads drains to 0; steady state at wait = 2(cur)+2(next).
// Epilogue: Q,K fp16 [bh][s][dh]; V fp16 transposed [bh][dh][s].
// ---------------------------------------------------------------------------
__global__ __launch_bounds__(512) void restore_mega(
    const float* __restrict__ hQ, const float* __restrict__ wQ,
    const float* __restrict__ hK, const float* __restrict__ wK,
    const float* __restrict__ hV, const float* __restrict__ wV,
    const u16* __restrict__ Rqk, const u16* __restrict__ Rv,
    u16* __restrict__ Qf, u16* __restrict__ Kf, u16* __restrict__ Vt,
    int* __restrict__ queue)
{
    __shared__ int sjob;
    __shared__ u16 Blds[2][8192];      // 32 KB: dbuf B tiles 128x64 fp16
    __shared__ float wsp[128 * 33];    // 16.5 KB: wr splat, [m][33] fp32

    const int tid = threadIdx.x;
    if (tid == 0) {
        int xcd = get_xcd();
        int job = -1;
        for (int t = 0; t < 8; ++t) {
            int qi = (xcd + t) & 7;
            int j = atomicAdd(&queue[qi], 1);
            if (j < 96) { job = qi * 96 + j; break; }
        }
        sjob = job;
    }
    __syncthreads();
    const int job = sjob;
    if (job < 0) return;
    const int qi   = job / 96;
    const int j    = job % 96;
    const int p    = qi * 12 + (j >> 3);      // (sel,rowt) pair owned by XCD qi
    const int sel  = p >> 5;                  // 0=Q,1=K,2=V
    const int rowt = p & 31;
    const int ct   = j & 7;
    const float* hA = (sel == 0) ? hQ : (sel == 1) ? hK : hV;
    const float* wA = (sel == 0) ? wQ : (sel == 1) ? wK : wV;
    const u16* Bg = (sel < 2) ? Rqk : Rv;
    const int K = 2048;
    const int row0 = rowt * 128, col0 = ct * 128;

    const int lane = tid & 63;
    const int wv   = tid >> 6;                // 0..7
    const int q    = lane >> 4;
    const int tn   = lane & 15;
    const int wm   = (wv >> 1) * 32;          // 4 row-groups x 32 rows
    const int wn   = (wv & 1) * 64;           // 2 col-groups x 64 cols
    const int wuni = (tid & 0x1C0) * 8;       // wave-uniform LDS base (u16)

    // wr -> LDS splat: thread loads 8 consecutive of row (tid>>2)
    {
        const int m = tid >> 2, n0 = (tid & 3) * 8;
        const float* wp = wA + (size_t)(row0 + m) * 32 + n0;
        float4 a = *(const float4*)wp;
        float4 b = *(const float4*)(wp + 4);
        float* d = wsp + m * 33 + n0;
        d[0] = a.x; d[1] = a.y; d[2] = a.z; d[3] = a.w;
        d[4] = b.x; d[5] = b.y; d[6] = b.z; d[7] = b.w;
    }

    // h-slice -> registers (fp32, exact): hr[i][sub][e] =
    //   h[row0 + wm + i*16 + tn][sub*32 + q*8 + e]; fixed for entire K-loop.
    float hr[2][2][8];
#pragma unroll
    for (int i = 0; i < 2; ++i) {
        const float* hp = hA + (size_t)(row0 + wm + i * 16 + tn) * 64 + q * 8;
#pragma unroll
        for (int sub = 0; sub < 2; ++sub) {
            float4 v0 = *(const float4*)(hp + sub * 32);
            float4 v1 = *(const float4*)(hp + sub * 32 + 4);
            hr[i][sub][0] = v0.x; hr[i][sub][1] = v0.y;
            hr[i][sub][2] = v0.z; hr[i][sub][3] = v0.w;
            hr[i][sub][4] = v1.x; hr[i][sub][5] = v1.y;
            hr[i][sub][6] = v1.z; hr[i][sub][7] = v1.w;
        }
    }

    // B stage: 128x64 tile (64-half rows, XOR-swizzled chunks; 2 loads/thread)
    auto stageB = [&](u16* dst, int kk) {
#pragma unroll
        for (int shot = 0; shot < 2; ++shot) {
            int sl = shot * 512 + tid;
            int m = sl >> 3, s = sl & 7, g = s ^ (m & 7);
            async_copy16(Bg + (size_t)(col0 + m) * K + kk * 64 + g * 8,
                         dst + shot * 4096 + wuni);
        }
    };

    f32x4 acc[2][4];
#pragma unroll
    for (int i = 0; i < 2; ++i)
#pragma unroll
        for (int jj = 0; jj < 4; ++jj) acc[i][jj] = 0.f;

    stageB(Blds[0], 0);
    __syncthreads();            // drains ALL vmem (hr/wsp/buf0): count starts 0

    int cur = 0;
    for (int kk = 0; kk < 32; ++kk) {    // BK=64 per iteration
        if (kk + 1 < 32) stageB(Blds[cur ^ 1], kk + 1);   // +2 outstanding

        // af construction (registers + wsp LDS) overlaps the load flight
        float wrv[2];
#pragma unroll
        for (int i = 0; i < 2; ++i)
            wrv[i] = wsp[(wm + i * 16 + tn) * 33 + kk];
        hfrag af[2][2];
#pragma unroll
        for (int sub = 0; sub < 2; ++sub)
#pragma unroll
            for (int i = 0; i < 2; ++i)
#pragma unroll
                for (int e = 0; e < 8; ++e)
                    af[sub][i][e] = (_Float16)(hr[i][sub][e] * wrv[i]);

        // wait ONLY cur's 2 loads (oldest); next's 2 stay in flight
        if (kk + 1 < 32) asm volatile("s_waitcnt vmcnt(2)" ::: "memory");
        else             asm volatile("s_waitcnt vmcnt(0)" ::: "memory");
        asm volatile("s_barrier" ::: "memory");   // all waves: cur complete

        const u16* Bb = Blds[cur];
#pragma unroll
        for (int sub = 0; sub < 2; ++sub) {
            hfrag bh[4];
#pragma unroll
            for (int jj = 0; jj < 4; ++jj) {
                int n = wn + jj * 16 + tn;
                int slt = (sub * 4 + q) ^ (n & 7);
                bh[jj] = *(const hfrag*)(Bb + n * 64 + slt * 8);
            }
#pragma unroll
            for (int i = 0; i < 2; ++i)
#pragma unroll
                for (int jj = 0; jj < 4; ++jj)
                    acc[i][jj] = mfma_f16(af[sub][i], bh[jj], acc[i][jj]);
        }
        asm volatile("s_barrier" ::: "memory");   // reads done before overwrite
        cur ^= 1;
    }

    // ---- epilogue ----------------------------------------------------------
#pragma unroll
    for (int i = 0; i < 2; ++i)
#pragma unroll
        for (int jj = 0; jj < 4; ++jj)
#pragma unroll
            for (int rg = 0; rg < 4; ++rg) {
                int row = row0 + wm + i * 16 + q * 4 + rg;
                int col = col0 + wn + jj * 16 + tn;
                float v = acc[i][jj][rg];
                if (sel < 2) {
                    size_t ix = (((size_t)(row >> 11) * 16 + (col >> 6)) << 17)
                              | ((size_t)(row & 2047) << 6) | (size_t)(col & 63);
                    ((sel == 0) ? Qf : Kf)[ix] = f2h(v);
                } else {
                    size_t ix = ((((size_t)(row >> 11) * 16 + (col >> 6)) * 64
                                 + (size_t)(col & 63)) << 11) | (size_t)(row & 2047);
                    Vt[ix] = f2h(v);
                }
            }
}

// ---------------------------------------------------------------------------
// generic staged tile: 64-half rows, XOR-swizzled chunks (pairs with the
// (c ^ (row&7)) read pattern).  SHOTS*256*8 halves total.
// ---------------------------------------------------------------------------
template<int SHOTS>
__device__ __forceinline__ void stage_tile(u16* dst, const u16* src, int rowstride,
                                           int tid, int wuni)
{
#pragma unroll
    for (int shot = 0; shot < SHOTS; ++shot) {
        int sl = shot * 256 + tid;
        int m = sl >> 3, s = sl & 7, g = s ^ (m & 7);
        async_copy16(src + (size_t)m * rowstride + g * 8, dst + shot * 2048 + wuni);
    }
}

// ---------------------------------------------------------------------------
// K-split MFMA flash attention, fp16. 1-D grid 8192: bh in low bits so
// same-(bid%8) blocks share K/V slices (2 MB) if round-robin holds.
// Q,K,V,P all fp16; QK = 2 MFMAs, PV = 8 MFMAs per 64-key tile.
// K/V double-buffered (sQ reused as K-buf 1 after the qf prologue load).
// ---------------------------------------------------------------------------
__global__ __launch_bounds__(256) void flash_part(const u16* __restrict__ Qf_g,
                                                  const u16* __restrict__ Kf_g,
                                                  const u16* __restrict__ Vt_g,
                                                  u16* __restrict__ Opart,
                                                  float* __restrict__ ml)
{
    const int bid = blockIdx.x;
    const int idx = bid >> 3;
    const int bh  = (bid & 7) + 8 * (idx & 3);
    const int rest = idx >> 2;              // 0..255
    const int qb = 31 - (rest >> 3);        // heavy first
    const int c  = rest & 7;
    const int g  = qb >> 2, rr = qb & 3;
    const int nch = g + 1;
    if (c >= nch) return;
    const int q0 = qb * 64;
    const int slot = bh * 144 + (qb + 2 * g * (g - 1) + rr * g) + c;

    const int tid = threadIdx.x;
    const int lane = tid & 63;
    const int wv = tid >> 6;
    const int q = lane >> 4;
    const int tn = lane & 15;
    const int wuni = (tid & 192) * 8;

    __shared__ u16 smem[20480];             // 40 KB
    u16* sQ  = smem;                        // K-buffer 1 after prologue
    u16* sK0 = smem + 4096;
    u16* sV0 = smem + 8192;
    u16* sV1 = smem + 12288;
    u16* sP  = smem + 16384;

    const size_t kbase = (size_t)bh * 2048 * 64;
    const size_t vbase = (size_t)bh * 64 * 2048;
    const int kt0    = 4 * c;
    const int kt_end = min(4 * c + 3, qb);

    // prologue: stage Q + first K/V tile together
    const size_t qoff = ((size_t)bh * 2048 + q0) * 64;
    stage_tile<2>(sQ, Qf_g + qoff, 64, tid, wuni);
    stage_tile<2>(sK0, Kf_g + kbase + (size_t)(kt0 * 64) * 64, 64, tid, wuni);
    stage_tile<2>(sV0, Vt_g + vbase + kt0 * 64, 2048, tid, wuni);
    __syncthreads();

    hfrag qf[2];
#pragma unroll
    for (int ks = 0; ks < 2; ++ks) {
        int m = wv * 16 + tn;
        int slt = (ks * 4 + q) ^ (m & 7);
        qf[ks] = *(const hfrag*)(sQ + m * 64 + slt * 8);
    }
    __syncthreads();   // all waves hold qf before sQ is reused as K-buf 1

    float m_i[4], l_i[4];
    f32x4 acc_o[4];
#pragma unroll
    for (int ri = 0; ri < 4; ++ri) { m_i[ri] = -3.0e38f; l_i[ri] = 0.f; }
#pragma unroll
    for (int dt = 0; dt < 4; ++dt) acc_o[dt] = 0.f;

    int cur = 0;
    for (int kt = kt0; kt <= kt_end; ++kt) {
        const u16* sK = cur ? sQ : sK0;
        const u16* sV = cur ? sV1 : sV0;
        if (kt < kt_end) {
            u16* nK = cur ? sK0 : sQ;
            u16* nV = cur ? sV0 : sV1;
            const int k1 = (kt + 1) * 64;
            stage_tile<2>(nK, Kf_g + kbase + (size_t)k1 * 64, 64, tid, wuni);
            stage_tile<2>(nV, Vt_g + vbase + k1, 2048, tid, wuni);
        }

        // QK^T fp16
        f32x4 accs[4];
#pragma unroll
        for (int n = 0; n < 4; ++n) accs[n] = 0.f;
#pragma unroll
        for (int n = 0; n < 4; ++n) {
            int r = n * 16 + tn;
#pragma unroll
            for (int ks = 0; ks < 2; ++ks) {
                int slt = (ks * 4 + q) ^ (r & 7);
                hfrag kf = *(const hfrag*)(sK + r * 64 + slt * 8);
                accs[n] = mfma_f16(qf[ks], kf, accs[n]);
            }
        }
        const bool diag = (kt == qb);
#pragma unroll
        for (int n = 0; n < 4; ++n)
#pragma unroll
            for (int ri = 0; ri < 4; ++ri) {
                float v = accs[n][ri] * 0.125f;
                if (diag && (n * 16 + tn > wv * 16 + q * 4 + ri)) v = -3.0e38f;
                accs[n][ri] = v;
            }
        // online softmax (rows across 16-lane quads)
        float alpha[4], mnew[4], ssum[4];
#pragma unroll
        for (int ri = 0; ri < 4; ++ri) {
            float mx = fmaxf(fmaxf(accs[0][ri], accs[1][ri]),
                             fmaxf(accs[2][ri], accs[3][ri]));
#pragma unroll
            for (int xm = 1; xm < 16; xm <<= 1)
                mx = fmaxf(mx, __shfl_xor(mx, xm, 64));
            mnew[ri] = fmaxf(m_i[ri], mx);
            alpha[ri] = __expf(m_i[ri] - mnew[ri]);
            m_i[ri] = mnew[ri];
            ssum[ri] = 0.f;
        }
#pragma unroll
        for (int n = 0; n < 4; ++n)
#pragma unroll
            for (int ri = 0; ri < 4; ++ri) {
                float p = __expf(accs[n][ri] - mnew[ri]);
                ssum[ri] += p;
                int m = wv * 16 + q * 4 + ri;
                int cc = n * 16 + tn;
                int slt = (cc >> 3) ^ (m & 7);
                sP[m * 64 + slt * 8 + (cc & 7)] = f2h(p);
            }
#pragma unroll
        for (int ri = 0; ri < 4; ++ri) {
            float sm = ssum[ri];
#pragma unroll
            for (int xm = 1; xm < 16; xm <<= 1)
                sm += __shfl_xor(sm, xm, 64);
            l_i[ri] = l_i[ri] * alpha[ri] + sm;
#pragma unroll
            for (int dt = 0; dt < 4; ++dt) acc_o[dt][ri] *= alpha[ri];
        }
        // PV fp16 (wave-local sP rows)
#pragma unroll
        for (int ks = 0; ks < 2; ++ks) {
            int m = wv * 16 + tn;
            int slt = (ks * 4 + q) ^ (m & 7);
            hfrag pf = *(const hfrag*)(sP + m * 64 + slt * 8);
#pragma unroll
            for (int dt = 0; dt < 4; ++dt) {
                int d = dt * 16 + tn;
                int vslt = (ks * 4 + q) ^ (d & 7);
                hfrag vf = *(const hfrag*)(sV + d * 64 + vslt * 8);
                acc_o[dt] = mfma_f16(pf, vf, acc_o[dt]);
            }
        }
        __syncthreads();   // drains stage(next); frees cur buffers for reuse
        cur ^= 1;
    }

    // partials: un-normalized O (bf16) + m,l (fp32)
#pragma unroll
    for (int dt = 0; dt < 4; ++dt)
#pragma unroll
        for (int ri = 0; ri < 4; ++ri) {
            int row = wv * 16 + q * 4 + ri;
            Opart[(size_t)slot * 4096 + row * 64 + dt * 16 + tn] = f2bf(acc_o[dt][ri]);
        }
    if (tn == 0) {
#pragma unroll
        for (int ri = 0; ri < 4; ++ri) {
            int row = wv * 16 + q * 4 + ri;
            ml[(size_t)slot * 128 + row]      = m_i[ri];
            ml[(size_t)slot * 128 + 64 + row] = l_i[ri];
        }
    }
}

// ---------------------------------------------------------------------------
// Combine partials -> bf16 [bs][d]
// ---------------------------------------------------------------------------
__global__ __launch_bounds__(256) void flash_combine(const u16* __restrict__ Opart,
                                                     const float* __restrict__ ml,
                                                     u16* __restrict__ Am)
{
    const int qb = blockIdx.x, bh = blockIdx.y;
    const int g = qb >> 2, rr = qb & 3;
    const int nch = g + 1;
    const int base = bh * 144 + (qb + 2 * g * (g - 1) + rr * g);
    const int tid = threadIdx.x;
    const int row = tid >> 2;
    const int c0  = (tid & 3) * 16;

    float mstar = -3.0e38f;
    float mc[8];
#pragma unroll
    for (int c = 0; c < 8; ++c) {
        if (c < nch) {
            mc[c] = ml[(size_t)(base + c) * 128 + row];
            mstar = fmaxf(mstar, mc[c]);
        }
    }
    float lstar = 0.f, wc[8];
#pragma unroll
    for (int c = 0; c < 8; ++c) {
        if (c < nch) {
            wc[c] = __expf(mc[c] - mstar);
            lstar += ml[(size_t)(base + c) * 128 + 64 + row] * wc[c];
        }
    }
    float o[16];
#pragma unroll
    for (int j = 0; j < 16; ++j) o[j] = 0.f;
    for (int c = 0; c < nch; ++c) {
        const u16* p = Opart + (size_t)(base + c) * 4096 + row * 64 + c0;
        u16x8 v0 = *(const u16x8*)p;
        u16x8 v1 = *(const u16x8*)(p + 8);
#pragma unroll
        for (int j = 0; j < 8; ++j) {
            o[j]     = fmaf(bf2f(v0[j]), wc[c], o[j]);
            o[j + 8] = fmaf(bf2f(v1[j]), wc[c], o[j + 8]);
        }
    }
    float inv = 1.0f / lstar;
    int srow = qb * 64 + row;
    size_t obase = ((size_t)(bh >> 4) * 2048 + srow) * 1024
                 + (size_t)((bh & 15) * 64 + c0);
    u16x8 w0, w1;
#pragma unroll
    for (int j = 0; j < 8; ++j) {
        w0[j] = f2bf(o[j] * inv);
        w1[j] = f2bf(o[j + 8] * inv);
    }
    *(u16x8*)(Am + obase)     = w0;
    *(u16x8*)(Am + obase + 8) = w1;
}

// ---------------------------------------------------------------------------
extern "C" void kernel_launch(void* const* d_in, const int* in_sizes, int n_in,
                              void* d_out, int out_size, void* d_ws, size_t ws_size,
                              hipStream_t stream)
{
    const float* x     = (const float*)d_in[0];
    const float* wfqkQ = (const float*)d_in[1];
    const float* wfqkK = (const float*)d_in[2];
    const float* wfv   = (const float*)d_in[3];
    const float* wrqkQ = (const float*)d_in[4];
    const float* wrqkK = (const float*)d_in[5];
    const float* wrv   = (const float*)d_in[6];
    const float* f_qk  = (const float*)d_in[7];
    const float* f_v   = (const float*)d_in[8];
    const float* r_qk  = (const float*)d_in[9];
    const float* r_v   = (const float*)d_in[10];
    const float* W_O   = (const float*)d_in[11];
    float* out = (float*)d_out;

    // Workspace layout (MB offsets).  Phases: 1 prep, 2 projV, 2b mixV,
    // 3 projQK, 3b mixQK, 4 restore, 5 flash, 6 combine, 7 outproj.
    //  [0,2)   WOb    1..7
    //  [2,6)   RqkT   1..4   -> Am [2,10) (6..7)
    //  [6,10)  RvT    1..4
    //  [10,18) x_hi   1..3   -> Opart [10,46) (5..6)
    //  [18,26) x_lo   1..3
    //  [26,30) FqkTh  1..3
    //  [30,34) FqkTl  1..3
    //  [34,38) FvT    1..2
    //  [42,45) h_q/h_k/h_v (2b/3b..4)
    //  [46,49) ml     5..6   (Opart [10,46) and ml [46,49) disjoint)
    //  [58,90) P      2..3b  -> Qf [58,66), Kf [66,74), Vt [74,82) (4..5)
    //  [84,..) queue  (4)
    const size_t MB = 1u << 20;
    char* w8 = (char*)d_ws;
    u16*  WOb   = (u16*)(w8 + 0);
    u16*  RqkT  = (u16*)(w8 + 2  * MB);
    u16*  RvT   = (u16*)(w8 + 6  * MB);
    u16*  x_hi  = (u16*)(w8 + 10 * MB);
    u16*  x_lo  = (u16*)(w8 + 18 * MB);
    u16*  FqkTh = (u16*)(w8 + 26 * MB);
    u16*  FqkTl = (u16*)(w8 + 30 * MB);
    u16*  FvT   = (u16*)(w8 + 34 * MB);
    float* h_q  = (float*)(w8 + 42 * MB);
    float* h_k  = (float*)(w8 + 43 * MB);
    float* h_v  = (float*)(w8 + 44 * MB);
    float* P    = (float*)(w8 + 58 * MB);
    u16*  Qf    = (u16*)(w8 + 58 * MB);
    u16*  Kf    = (u16*)(w8 + 66 * MB);
    u16*  Vt    = (u16*)(w8 + 74 * MB);
    u16*  Opart = (u16*)(w8 + 10 * MB);
    float* mlws = (float*)(w8 + 46 * MB);
    u16*  Am    = (u16*)(w8 + 2  * MB);
    int*  queue = (int*)(w8 + 84 * MB);

    dim3 blk(256);

    // casts / transposes (r_qk + r_v merged into one launch)
    cast_split<1><<<dim3(4096), blk, 0, stream>>>(x, x_hi, x_lo, 1024 * 1024);
    cast_split<0><<<dim3(1024), blk, 0, stream>>>(W_O, WOb, nullptr, 256 * 1024);
    transpose_cast<1><<<dim3(2, 32, 32), blk, 0, stream>>>(f_qk, FqkTh, FqkTl, 1024, 64, 1024);
    transpose_cast<0><<<dim3(2, 32, 32), blk, 0, stream>>>(f_v,  FvT,   nullptr, 1024, 64, 1024);
    transpose_cast_h2<<<dim3(32, 64, 2), blk, 0, stream>>>(r_qk, RqkT, r_v, RvT,
                                                           2048, 1024, 2048);

    // projV (bf16 single) + mix -> h_v
    gemm_mfma<0, 2><<<dim3(512), blk, 0, stream>>>(x_hi, nullptr, FvT, nullptr, P,
                                                   4096, 2048, 1024);
    mix_kernel<<<dim3(1024), blk, 0, stream>>>(P, wfv, nullptr, h_v, nullptr, 0);

    // projQK (bf16 split) + mix -> h_q, h_k
    gemm_mfma<1, 2><<<dim3(512), blk, 0, stream>>>(x_hi, x_lo, FqkTh, FqkTl, P,
                                                   4096, 2048, 1024);
    mix_kernel<<<dim3(1024), blk, 0, stream>>>(P, wfqkQ, wfqkK, h_q, h_k, 1);

    // fused restore (fp16, on-the-fly A, BK=64 dbuf + counted vmcnt)
    hipMemsetAsync(queue, 0, 8 * sizeof(int), stream);
    restore_mega<<<dim3(768), dim3(512), 0, stream>>>(h_q, wrqkQ, h_k, wrqkK,
                                                      h_v, wrv, RqkT, RvT,
                                                      Qf, Kf, Vt, queue);

    // K-split flash attention (fp16, K/V dbuf): partials + combine
    flash_part<<<dim3(8192), blk, 0, stream>>>(Qf, Kf, Vt, Opart, mlws);
    flash_combine<<<dim3(32, 32), blk, 0, stream>>>(Opart, mlws, Am);

    // output projection (bf16)
    gemm_mfma<0, 1><<<dim3(256), blk, 0, stream>>>(Am, nullptr, WOb, nullptr, out,
                                                   4096, 1024, 1024);
}

// Round 17
// 386.412 us; speedup vs baseline: 1.0639x; 1.0639x over previous
//
#include <hip/hip_runtime.h>
#include <hip/hip_bf16.h>
#include <cstdint>
#include <cstddef>

// B=2, S=2048, D=1024, R=64, H=16, DH=64, N=32; BS=4096
typedef unsigned short u16;
typedef short bfrag __attribute__((ext_vector_type(8)));      // 8 bf16
typedef _Float16 hfrag __attribute__((ext_vector_type(8)));   // 8 fp16
typedef float f32x4 __attribute__((ext_vector_type(4)));
typedef u16 u16x8 __attribute__((ext_vector_type(8)));

__device__ __forceinline__ u16 f2bf(float v) {
    union { float f; unsigned u; } a; a.f = v;
    unsigned r = a.u + 0x7fff + ((a.u >> 16) & 1);   // RNE
    return (u16)(r >> 16);
}
__device__ __forceinline__ float bf2f(u16 u) {
    union { unsigned u; float f; } a; a.u = ((unsigned)u) << 16;
    return a.f;
}
__device__ __forceinline__ u16 f2h(float v) {
    union { _Float16 h; u16 u; } a; a.h = (_Float16)v;
    return a.u;
}
__device__ __forceinline__ f32x4 mfma_bf16(bfrag a, bfrag b, f32x4 c) {
    return __builtin_amdgcn_mfma_f32_16x16x32_bf16(a, b, c, 0, 0, 0);
}
__device__ __forceinline__ f32x4 mfma_f16(hfrag a, hfrag b, f32x4 c) {
    return __builtin_amdgcn_mfma_f32_16x16x32_f16(a, b, c, 0, 0, 0);
}
__device__ __forceinline__ void async_copy16(const void* g, void* l) {
    __builtin_amdgcn_global_load_lds(
        (const __attribute__((address_space(1))) unsigned*)g,
        (__attribute__((address_space(3))) unsigned*)l, 16, 0, 0);
}
__device__ __forceinline__ int get_xcd() {
    unsigned x;
    asm volatile("s_getreg_b32 %0, hwreg(HW_REG_XCC_ID)" : "=s"(x));
    return (int)(x & 7);
}

// ---------------------------------------------------------------------------
// elementwise cast fp32 -> bf16 hi (+lo if SPLIT); n4 = count/4
// ---------------------------------------------------------------------------
template<int SPLIT>
__global__ __launch_bounds__(256) void cast_split(const float* __restrict__ s,
                                                  u16* __restrict__ dh,
                                                  u16* __restrict__ dl, int n4)
{
    int i = blockIdx.x * 256 + threadIdx.x;
    if (i >= n4) return;
    float4 v = ((const float4*)s)[i];
    float vv[4] = {v.x, v.y, v.z, v.w};
    ushort4 h, l;
    u16* hp = (u16*)&h; u16* lp = (u16*)&l;
#pragma unroll
    for (int e = 0; e < 4; ++e) {
        u16 hb = f2bf(vv[e]);
        hp[e] = hb;
        if (SPLIT) lp[e] = f2bf(vv[e] - bf2f(hb));
    }
    ((ushort4*)dh)[i] = h;
    if (SPLIT) ((ushort4*)dl)[i] = l;
}

// ---------------------------------------------------------------------------
// transpose + cast: dst[z*C + c][r] = src[z*R*C + r*C + c]; dst pitch dpitch.
// MODE 0: bf16 single; MODE 1: bf16 hi/lo split; MODE 2: fp16 single.
// ---------------------------------------------------------------------------
template<int MODE>
__global__ __launch_bounds__(256) void transpose_cast(const float* __restrict__ src,
                                                      u16* __restrict__ dh,
                                                      u16* __restrict__ dl,
                                                      int R, int C, int dpitch)
{
    __shared__ float t[32][33];
    int z = blockIdx.z;
    const float* s = src + (size_t)z * R * C;
    int r0 = blockIdx.y * 32, c0 = blockIdx.x * 32;
    int tx = threadIdx.x & 31, ty = threadIdx.x >> 5;
#pragma unroll
    for (int p = 0; p < 4; ++p)
        t[ty + p * 8][tx] = s[(size_t)(r0 + ty + p * 8) * C + c0 + tx];
    __syncthreads();
#pragma unroll
    for (int p = 0; p < 4; ++p) {
        int rr = ty + p * 8;
        float v = t[tx][rr];
        size_t di = (size_t)(z * C + c0 + rr) * dpitch + r0 + tx;
        if (MODE == 2) {
            dh[di] = f2h(v);
        } else {
            u16 hb = f2bf(v);
            dh[di] = hb;
            if (MODE == 1) dl[di] = f2bf(v - bf2f(hb));
        }
    }
}

// ---------------------------------------------------------------------------
// merged fp16 transpose for r_qk and r_v (same shape): gridDim.z selects the
// tensor.  Element mapping/rounding identical to transpose_cast<2>.
// ---------------------------------------------------------------------------
__global__ __launch_bounds__(256) void transpose_cast_h2(
    const float* __restrict__ s0, u16* __restrict__ d0,
    const float* __restrict__ s1, u16* __restrict__ d1,
    int R, int C, int dpitch)
{
    __shared__ float t[32][33];
    const float* s = blockIdx.z ? s1 : s0;
    u16* dh        = blockIdx.z ? d1 : d0;
    int r0 = blockIdx.y * 32, c0 = blockIdx.x * 32;
    int tx = threadIdx.x & 31, ty = threadIdx.x >> 5;
#pragma unroll
    for (int p = 0; p < 4; ++p)
        t[ty + p * 8][tx] = s[(size_t)(r0 + ty + p * 8) * C + c0 + tx];
    __syncthreads();
#pragma unroll
    for (int p = 0; p < 4; ++p) {
        int rr = ty + p * 8;
        dh[(size_t)(c0 + rr) * dpitch + r0 + tx] = f2h(t[tx][rr]);
    }
}

// ---------------------------------------------------------------------------
// MFMA bf16 GEMM 128x128, BK=32 (project / outproj).
// XCD-inverted tiling: xq = bid&7 (~XCD under round-robin dispatch) owns
// rowt in [xq*RP, xq*RP+RP) (RP = M/128/8) and iterates ct -> the A row-slice
// stays L2-resident per XCD; B streams via L3 (small footprint).
// Double-buffered LDS, ONE barrier per K-step.
// ---------------------------------------------------------------------------
template<int SPLIT, int CTH>
__global__ __launch_bounds__(256) void gemm_mfma(const u16* __restrict__ Agh,
                                                 const u16* __restrict__ Agl,
                                                 const u16* __restrict__ Bgh,
                                                 const u16* __restrict__ Bgl,
                                                 float* __restrict__ C,
                                                 int M, int N, int K)
{
    constexpr int HB = SPLIT ? 16384 : 8192;   // u16 per LDS buffer
    __shared__ u16 lds[2 * HB];

    const int bid = blockIdx.x;
    const int xq  = bid & 7;
    const int s   = bid >> 3;
    const int RP  = (M >> 7) >> 3;            // rowts per XCD (=4)
    const int rowt = xq * RP + (s % RP);
    const int ct   = s / RP;
    const int row0 = rowt * 128;
    const int col0 = ct * 128;

    const int tid  = threadIdx.x;
    const int lane = tid & 63;
    const int wv   = tid >> 6;
    const int q    = lane >> 4;
    const int tn   = lane & 15;
    const int wm   = (wv >> 1) * 64;
    const int wn   = (wv & 1) * 64;
    const int wbase = (tid & 192) * 8;

    auto stage = [&](u16* base, int k0) {
        u16* Ath = base;
        u16* Atl = SPLIT ? (base + 4096) : base;
        u16* Bth = base + (SPLIT ? 8192 : 4096);
        u16* Btl = SPLIT ? (base + 12288) : base;
#pragma unroll
        for (int shot = 0; shot < 2; ++shot) {
            int G = tid + shot * 256;
            int row = G >> 2, kgs = G & 3;
            int kgg = kgs ^ ((row >> 1) & 3);
            size_t goffB = (size_t)(col0 + row) * K + k0 + kgg * 8;
            async_copy16(Bgh + goffB, Bth + shot * 2048 + wbase);
            if (SPLIT) async_copy16(Bgl + goffB, Btl + shot * 2048 + wbase);
            size_t goffA = (size_t)(row0 + row) * K + k0 + kgg * 8;
            async_copy16(Agh + goffA, Ath + shot * 2048 + wbase);
            if (SPLIT) async_copy16(Agl + goffA, Atl + shot * 2048 + wbase);
        }
    };

    f32x4 acc[4][4];
#pragma unroll
    for (int i = 0; i < 4; ++i)
#pragma unroll
        for (int j = 0; j < 4; ++j) acc[i][j] = 0.f;

    stage(lds, 0);
    __syncthreads();                     // buf0 ready

    int cur = 0;
    const int NT = K >> 5;
    for (int n = 0; n < NT; ++n) {
        if (n + 1 < NT) stage(lds + (cur ^ 1) * HB, (n + 1) * 32);

        const u16* base = lds + cur * HB;
        const u16* Ath = base;
        const u16* Atl = SPLIT ? (base + 4096) : base;
        const u16* Bth = base + (SPLIT ? 8192 : 4096);
        const u16* Btl = SPLIT ? (base + 12288) : base;

        bfrag ah[4], bh[4], al[4], bl[4];
#pragma unroll
        for (int i = 0; i < 4; ++i) {
            int m = wm + i * 16 + tn;
            int g = m * 4 + (q ^ ((m >> 1) & 3));
            ah[i] = *(const bfrag*)(Ath + g * 8);
            if (SPLIT) al[i] = *(const bfrag*)(Atl + g * 8);
        }
#pragma unroll
        for (int j = 0; j < 4; ++j) {
            int n2 = wn + j * 16 + tn;
            int g = n2 * 4 + (q ^ ((n2 >> 1) & 3));
            bh[j] = *(const bfrag*)(Bth + g * 8);
            if (SPLIT) bl[j] = *(const bfrag*)(Btl + g * 8);
        }
#pragma unroll
        for (int i = 0; i < 4; ++i)
#pragma unroll
            for (int j = 0; j < 4; ++j) {
                acc[i][j] = mfma_bf16(ah[i], bh[j], acc[i][j]);
                if (SPLIT) {
                    acc[i][j] = mfma_bf16(ah[i], bl[j], acc[i][j]);
                    acc[i][j] = mfma_bf16(al[i], bh[j], acc[i][j]);
                }
            }
        __syncthreads();
        cur ^= 1;
    }

#pragma unroll
    for (int i = 0; i < 4; ++i)
#pragma unroll
        for (int j = 0; j < 4; ++j)
#pragma unroll
            for (int rg = 0; rg < 4; ++rg) {
                int row = row0 + wm + i * 16 + q * 4 + rg;
                int col = col0 + wn + j * 16 + tn;
                C[(size_t)row * N + col] = acc[i][j][rg];
            }
}

// ---------------------------------------------------------------------------
// Mix: h1[bs,r] = sum_n w1[bs,n] * P[bs, n*64+r]  (optionally h2 with w2)
// (verified original fmaf chain; h consumed in-register by restore_mega)
// ---------------------------------------------------------------------------
__global__ __launch_bounds__(256) void mix_kernel(const float* __restrict__ P,
                                                  const float* __restrict__ w1,
                                                  const float* __restrict__ w2,
                                                  float* __restrict__ h1,
                                                  float* __restrict__ h2,
                                                  int two)
{
    int tid = blockIdx.x * 256 + threadIdx.x;
    int bs = tid >> 6;
    int r  = tid & 63;
    const float* Pp = P + (size_t)bs * 2048 + r;
    float a = 0.f, b = 0.f;
#pragma unroll
    for (int n = 0; n < 32; ++n) {
        float p = Pp[n * 64];
        a = fmaf(w1[bs * 32 + n], p, a);
        if (two) b = fmaf(w2[bs * 32 + n], p, b);
    }
    h1[tid] = a;
    if (two) h2[tid] = b;
}

// ---------------------------------------------------------------------------
// Fused restore GEMMs, fp16, 128x128 tiles, XCD work-queue, 512-thread
// blocks, on-the-fly A (never materialized): A[m,k] = fp16(h[m,k&63] *
// wr[m,k>>6]) from register-resident h (32 fp32/thread) + LDS-splatted wr.
// BK=64 single-buffer B-staging, 16 MFMAs per barrier-pair (round-13/15
// verified best; dbuf/BK/occupancy/traffic/counted-vmcnt levers all measured
// <= neutral -- ~98us is this structure's floor).  fp32*fp32 -> fp16 single
// rounding + k-order unchanged -> outputs bit-identical.  LDS 32.5 KB.
// Epilogue: Q,K fp16 [bh][s][dh]; V fp16 transposed [bh][dh][s].
// ---------------------------------------------------------------------------
__global__ __launch_bounds__(512) void restore_mega(
    const float* __restrict__ hQ, const float* __restrict__ wQ,
    const float* __restrict__ hK, const float* __restrict__ wK,
    const float* __restrict__ hV, const float* __restrict__ wV,
    const u16* __restrict__ Rqk, const u16* __restrict__ Rv,
    u16* __restrict__ Qf, u16* __restrict__ Kf, u16* __restrict__ Vt,
    int* __restrict__ queue)
{
    __shared__ int sjob;
    __shared__ u16 Blds[8192];         // 16 KB: B tile 128x64 fp16 (64-half rows)
    __shared__ float wsp[128 * 33];    // 16.5 KB: wr splat, [m][33] fp32

    const int tid = threadIdx.x;
    if (tid == 0) {
        int xcd = get_xcd();
        int job = -1;
        for (int t = 0; t < 8; ++t) {
            int qi = (xcd + t) & 7;
            int j = atomicAdd(&queue[qi], 1);
            if (j < 96) { job = qi * 96 + j; break; }
        }
        sjob = job;
    }
    __syncthreads();
    const int job = sjob;
    if (job < 0) return;
    const int qi   = job / 96;
    const int j    = job % 96;
    const int p    = qi * 12 + (j >> 3);      // (sel,rowt) pair owned by XCD qi
    const int sel  = p >> 5;                  // 0=Q,1=K,2=V
    const int rowt = p & 31;
    const int ct   = j & 7;
    const float* hA = (sel == 0) ? hQ : (sel == 1) ? hK : hV;
    const float* wA = (sel == 0) ? wQ : (sel == 1) ? wK : wV;
    const u16* Bg = (sel < 2) ? Rqk : Rv;
    const int K = 2048;
    const int row0 = rowt * 128, col0 = ct * 128;

    const int lane = tid & 63;
    const int wv   = tid >> 6;                // 0..7
    const int q    = lane >> 4;
    const int tn   = lane & 15;
    const int wm   = (wv >> 1) * 32;          // 4 row-groups x 32 rows
    const int wn   = (wv & 1) * 64;           // 2 col-groups x 64 cols
    const int wuni = (tid & 0x1C0) * 8;       // wave-uniform LDS base (u16)

    // wr -> LDS splat: thread loads 8 consecutive of row (tid>>2)
    {
        const int m = tid >> 2, n0 = (tid & 3) * 8;
        const float* wp = wA + (size_t)(row0 + m) * 32 + n0;
        float4 a = *(const float4*)wp;
        float4 b = *(const float4*)(wp + 4);
        float* d = wsp + m * 33 + n0;
        d[0] = a.x; d[1] = a.y; d[2] = a.z; d[3] = a.w;
        d[4] = b.x; d[5] = b.y; d[6] = b.z; d[7] = b.w;
    }

    // h-slice -> registers (fp32, exact): hr[i][sub][e] =
    //   h[row0 + wm + i*16 + tn][sub*32 + q*8 + e]; fixed for entire K-loop.
    float hr[2][2][8];
#pragma unroll
    for (int i = 0; i < 2; ++i) {
        const float* hp = hA + (size_t)(row0 + wm + i * 16 + tn) * 64 + q * 8;
#pragma unroll
        for (int sub = 0; sub < 2; ++sub) {
            float4 v0 = *(const float4*)(hp + sub * 32);
            float4 v1 = *(const float4*)(hp + sub * 32 + 4);
            hr[i][sub][0] = v0.x; hr[i][sub][1] = v0.y;
            hr[i][sub][2] = v0.z; hr[i][sub][3] = v0.w;
            hr[i][sub][4] = v1.x; hr[i][sub][5] = v1.y;
            hr[i][sub][6] = v1.z; hr[i][sub][7] = v1.w;
        }
    }

    f32x4 acc[2][4];
#pragma unroll
    for (int i = 0; i < 2; ++i)
#pragma unroll
        for (int jj = 0; jj < 4; ++jj) acc[i][jj] = 0.f;

    __syncthreads();                     // wsp visible before first read

    for (int kk = 0; kk < 32; ++kk) {    // BK=64 per iteration
        float wrv[2];
#pragma unroll
        for (int i = 0; i < 2; ++i)
            wrv[i] = wsp[(wm + i * 16 + tn) * 33 + kk];

        // stage B 128x64 tile (64-half rows, XOR-swizzled chunks; 2 shots)
#pragma unroll
        for (int shot = 0; shot < 2; ++shot) {
            int sl = shot * 512 + tid;
            int m = sl >> 3, s = sl & 7, g = s ^ (m & 7);
            async_copy16(Bg + (size_t)(col0 + m) * K + kk * 64 + g * 8,
                         Blds + shot * 4096 + wuni);
        }
        __syncthreads();                 // B tile ready

#pragma unroll
        for (int sub = 0; sub < 2; ++sub) {
            hfrag bh[4];
#pragma unroll
            for (int jj = 0; jj < 4; ++jj) {
                int n = wn + jj * 16 + tn;
                int slt = (sub * 4 + q) ^ (n & 7);
                bh[jj] = *(const hfrag*)(Blds + n * 64 + slt * 8);
            }
            hfrag af[2];
#pragma unroll
            for (int i = 0; i < 2; ++i)
#pragma unroll
                for (int e = 0; e < 8; ++e)
                    af[i][e] = (_Float16)(hr[i][sub][e] * wrv[i]);
#pragma unroll
            for (int i = 0; i < 2; ++i)
#pragma unroll
                for (int jj = 0; jj < 4; ++jj)
                    acc[i][jj] = mfma_f16(af[i], bh[jj], acc[i][jj]);
        }
        __syncthreads();                 // protect Blds before next stage
    }

    // ---- epilogue ----------------------------------------------------------
#pragma unroll
    for (int i = 0; i < 2; ++i)
#pragma unroll
        for (int jj = 0; jj < 4; ++jj)
#pragma unroll
            for (int rg = 0; rg < 4; ++rg) {
                int row = row0 + wm + i * 16 + q * 4 + rg;
                int col = col0 + wn + jj * 16 + tn;
                float v = acc[i][jj][rg];
                if (sel < 2) {
                    size_t ix = (((size_t)(row >> 11) * 16 + (col >> 6)) << 17)
                              | ((size_t)(row & 2047) << 6) | (size_t)(col & 63);
                    ((sel == 0) ? Qf : Kf)[ix] = f2h(v);
                } else {
                    size_t ix = ((((size_t)(row >> 11) * 16 + (col >> 6)) * 64
                                 + (size_t)(col & 63)) << 11) | (size_t)(row & 2047);
                    Vt[ix] = f2h(v);
                }
            }
}

// ---------------------------------------------------------------------------
// generic staged tile: 64-half rows, XOR-swizzled chunks (pairs with the
// (c ^ (row&7)) read pattern).  SHOTS*256*8 halves total.
// ---------------------------------------------------------------------------
template<int SHOTS>
__device__ __forceinline__ void stage_tile(u16* dst, const u16* src, int rowstride,
                                           int tid, int wuni)
{
#pragma unroll
    for (int shot = 0; shot < SHOTS; ++shot) {
        int sl = shot * 256 + tid;
        int m = sl >> 3, s = sl & 7, g = s ^ (m & 7);
        async_copy16(src + (size_t)m * rowstride + g * 8, dst + shot * 2048 + wuni);
    }
}

// ---------------------------------------------------------------------------
// K-split MFMA flash attention, fp16. 1-D grid 8192: bh in low bits so
// same-(bid%8) blocks share K/V slices (2 MB) if round-robin holds.
// Q,K,V,P all fp16; QK = 2 MFMAs, PV = 8 MFMAs per 64-key tile.
// K/V double-buffered (sQ reused as K-buf 1 after the qf prologue load).
// ---------------------------------------------------------------------------
__global__ __launch_bounds__(256) void flash_part(const u16* __restrict__ Qf_g,
                                                  const u16* __restrict__ Kf_g,
                                                  const u16* __restrict__ Vt_g,
                                                  u16* __restrict__ Opart,
                                                  float* __restrict__ ml)
{
    const int bid = blockIdx.x;
    const int idx = bid >> 3;
    const int bh  = (bid & 7) + 8 * (idx & 3);
    const int rest = idx >> 2;              // 0..255
    const int qb = 31 - (rest >> 3);        // heavy first
    const int c  = rest & 7;
    const int g  = qb >> 2, rr = qb & 3;
    const int nch = g + 1;
    if (c >= nch) return;
    const int q0 = qb * 64;
    const int slot = bh * 144 + (qb + 2 * g * (g - 1) + rr * g) + c;

    const int tid = threadIdx.x;
    const int lane = tid & 63;
    const int wv = tid >> 6;
    const int q = lane >> 4;
    const int tn = lane & 15;
    const int wuni = (tid & 192) * 8;

    __shared__ u16 smem[20480];             // 40 KB
    u16* sQ  = smem;                        // K-buffer 1 after prologue
    u16* sK0 = smem + 4096;
    u16* sV0 = smem + 8192;
    u16* sV1 = smem + 12288;
    u16* sP  = smem + 16384;

    const size_t kbase = (size_t)bh * 2048 * 64;
    const size_t vbase = (size_t)bh * 64 * 2048;
    const int kt0    = 4 * c;
    const int kt_end = min(4 * c + 3, qb);

    // prologue: stage Q + first K/V tile together
    const size_t qoff = ((size_t)bh * 2048 + q0) * 64;
    stage_tile<2>(sQ, Qf_g + qoff, 64, tid, wuni);
    stage_tile<2>(sK0, Kf_g + kbase + (size_t)(kt0 * 64) * 64, 64, tid, wuni);
    stage_tile<2>(sV0, Vt_g + vbase + kt0 * 64, 2048, tid, wuni);
    __syncthreads();

    hfrag qf[2];
#pragma unroll
    for (int ks = 0; ks < 2; ++ks) {
        int m = wv * 16 + tn;
        int slt = (ks * 4 + q) ^ (m & 7);
        qf[ks] = *(const hfrag*)(sQ + m * 64 + slt * 8);
    }
    __syncthreads();   // all waves hold qf before sQ is reused as K-buf 1

    float m_i[4], l_i[4];
    f32x4 acc_o[4];
#pragma unroll
    for (int ri = 0; ri < 4; ++ri) { m_i[ri] = -3.0e38f; l_i[ri] = 0.f; }
#pragma unroll
    for (int dt = 0; dt < 4; ++dt) acc_o[dt] = 0.f;

    int cur = 0;
    for (int kt = kt0; kt <= kt_end; ++kt) {
        const u16* sK = cur ? sQ : sK0;
        const u16* sV = cur ? sV1 : sV0;
        if (kt < kt_end) {
            u16* nK = cur ? sK0 : sQ;
            u16* nV = cur ? sV0 : sV1;
            const int k1 = (kt + 1) * 64;
            stage_tile<2>(nK, Kf_g + kbase + (size_t)k1 * 64, 64, tid, wuni);
            stage_tile<2>(nV, Vt_g + vbase + k1, 2048, tid, wuni);
        }

        // QK^T fp16
        f32x4 accs[4];
#pragma unroll
        for (int n = 0; n < 4; ++n) accs[n] = 0.f;
#pragma unroll
        for (int n = 0; n < 4; ++n) {
            int r = n * 16 + tn;
#pragma unroll
            for (int ks = 0; ks < 2; ++ks) {
                int slt = (ks * 4 + q) ^ (r & 7);
                hfrag kf = *(const hfrag*)(sK + r * 64 + slt * 8);
                accs[n] = mfma_f16(qf[ks], kf, accs[n]);
            }
        }
        const bool diag = (kt == qb);
#pragma unroll
        for (int n = 0; n < 4; ++n)
#pragma unroll
            for (int ri = 0; ri < 4; ++ri) {
                float v = accs[n][ri] * 0.125f;
                if (diag && (n * 16 + tn > wv * 16 + q * 4 + ri)) v = -3.0e38f;
                accs[n][ri] = v;
            }
        // online softmax (rows across 16-lane quads)
        float alpha[4], mnew[4], ssum[4];
#pragma unroll
        for (int ri = 0; ri < 4; ++ri) {
            float mx = fmaxf(fmaxf(accs[0][ri], accs[1][ri]),
                             fmaxf(accs[2][ri], accs[3][ri]));
#pragma unroll
            for (int xm = 1; xm < 16; xm <<= 1)
                mx = fmaxf(mx, __shfl_xor(mx, xm, 64));
            mnew[ri] = fmaxf(m_i[ri], mx);
            alpha[ri] = __expf(m_i[ri] - mnew[ri]);
            m_i[ri] = mnew[ri];
            ssum[ri] = 0.f;
        }
#pragma unroll
        for (int n = 0; n < 4; ++n)
#pragma unroll
            for (int ri = 0; ri < 4; ++ri) {
                float p = __expf(accs[n][ri] - mnew[ri]);
                ssum[ri] += p;
                int m = wv * 16 + q * 4 + ri;
                int cc = n * 16 + tn;
                int slt = (cc >> 3) ^ (m & 7);
                sP[m * 64 + slt * 8 + (cc & 7)] = f2h(p);
            }
#pragma unroll
        for (int ri = 0; ri < 4; ++ri) {
            float sm = ssum[ri];
#pragma unroll
            for (int xm = 1; xm < 16; xm <<= 1)
                sm += __shfl_xor(sm, xm, 64);
            l_i[ri] = l_i[ri] * alpha[ri] + sm;
#pragma unroll
            for (int dt = 0; dt < 4; ++dt) acc_o[dt][ri] *= alpha[ri];
        }
        // PV fp16 (wave-local sP rows)
#pragma unroll
        for (int ks = 0; ks < 2; ++ks) {
            int m = wv * 16 + tn;
            int slt = (ks * 4 + q) ^ (m & 7);
            hfrag pf = *(const hfrag*)(sP + m * 64 + slt * 8);
#pragma unroll
            for (int dt = 0; dt < 4; ++dt) {
                int d = dt * 16 + tn;
                int vslt = (ks * 4 + q) ^ (d & 7);
                hfrag vf = *(const hfrag*)(sV + d * 64 + vslt * 8);
                acc_o[dt] = mfma_f16(pf, vf, acc_o[dt]);
            }
        }
        __syncthreads();   // drains stage(next); frees cur buffers for reuse
        cur ^= 1;
    }

    // partials: un-normalized O (bf16) + m,l (fp32)
#pragma unroll
    for (int dt = 0; dt < 4; ++dt)
#pragma unroll
        for (int ri = 0; ri < 4; ++ri) {
            int row = wv * 16 + q * 4 + ri;
            Opart[(size_t)slot * 4096 + row * 64 + dt * 16 + tn] = f2bf(acc_o[dt][ri]);
        }
    if (tn == 0) {
#pragma unroll
        for (int ri = 0; ri < 4; ++ri) {
            int row = wv * 16 + q * 4 + ri;
            ml[(size_t)slot * 128 + row]      = m_i[ri];
            ml[(size_t)slot * 128 + 64 + row] = l_i[ri];
        }
    }
}

// ---------------------------------------------------------------------------
// Combine partials -> bf16 [bs][d]
// ---------------------------------------------------------------------------
__global__ __launch_bounds__(256) void flash_combine(const u16* __restrict__ Opart,
                                                     const float* __restrict__ ml,
                                                     u16* __restrict__ Am)
{
    const int qb = blockIdx.x, bh = blockIdx.y;
    const int g = qb >> 2, rr = qb & 3;
    const int nch = g + 1;
    const int base = bh * 144 + (qb + 2 * g * (g - 1) + rr * g);
    const int tid = threadIdx.x;
    const int row = tid >> 2;
    const int c0  = (tid & 3) * 16;

    float mstar = -3.0e38f;
    float mc[8];
#pragma unroll
    for (int c = 0; c < 8; ++c) {
        if (c < nch) {
            mc[c] = ml[(size_t)(base + c) * 128 + row];
            mstar = fmaxf(mstar, mc[c]);
        }
    }
    float lstar = 0.f, wc[8];
#pragma unroll
    for (int c = 0; c < 8; ++c) {
        if (c < nch) {
            wc[c] = __expf(mc[c] - mstar);
            lstar += ml[(size_t)(base + c) * 128 + 64 + row] * wc[c];
        }
    }
    float o[16];
#pragma unroll
    for (int j = 0; j < 16; ++j) o[j] = 0.f;
    for (int c = 0; c < nch; ++c) {
        const u16* p = Opart + (size_t)(base + c) * 4096 + row * 64 + c0;
        u16x8 v0 = *(const u16x8*)p;
        u16x8 v1 = *(const u16x8*)(p + 8);
#pragma unroll
        for (int j = 0; j < 8; ++j) {
            o[j]     = fmaf(bf2f(v0[j]), wc[c], o[j]);
            o[j + 8] = fmaf(bf2f(v1[j]), wc[c], o[j + 8]);
        }
    }
    float inv = 1.0f / lstar;
    int srow = qb * 64 + row;
    size_t obase = ((size_t)(bh >> 4) * 2048 + srow) * 1024
                 + (size_t)((bh & 15) * 64 + c0);
    u16x8 w0, w1;
#pragma unroll
    for (int j = 0; j < 8; ++j) {
        w0[j] = f2bf(o[j] * inv);
        w1[j] = f2bf(o[j + 8] * inv);
    }
    *(u16x8*)(Am + obase)     = w0;
    *(u16x8*)(Am + obase + 8) = w1;
}

// ---------------------------------------------------------------------------
extern "C" void kernel_launch(void* const* d_in, const int* in_sizes, int n_in,
                              void* d_out, int out_size, void* d_ws, size_t ws_size,
                              hipStream_t stream)
{
    const float* x     = (const float*)d_in[0];
    const float* wfqkQ = (const float*)d_in[1];
    const float* wfqkK = (const float*)d_in[2];
    const float* wfv   = (const float*)d_in[3];
    const float* wrqkQ = (const float*)d_in[4];
    const float* wrqkK = (const float*)d_in[5];
    const float* wrv   = (const float*)d_in[6];
    const float* f_qk  = (const float*)d_in[7];
    const float* f_v   = (const float*)d_in[8];
    const float* r_qk  = (const float*)d_in[9];
    const float* r_v   = (const float*)d_in[10];
    const float* W_O   = (const float*)d_in[11];
    float* out = (float*)d_out;

    // Workspace layout (MB offsets).  Phases: 1 prep, 2 projV, 2b mixV,
    // 3 projQK, 3b mixQK, 4 restore, 5 flash, 6 combine, 7 outproj.
    //  [0,2)   WOb    1..7
    //  [2,6)   RqkT   1..4   -> Am [2,10) (6..7)
    //  [6,10)  RvT    1..4
    //  [10,18) x_hi   1..3   -> Opart [10,46) (5..6)
    //  [18,26) x_lo   1..3
    //  [26,30) FqkTh  1..3
    //  [30,34) FqkTl  1..3
    //  [34,38) FvT    1..2
    //  [42,45) h_q/h_k/h_v (2b/3b..4)
    //  [46,49) ml     5..6   (Opart [10,46) and ml [46,49) disjoint)
    //  [58,90) P      2..3b  -> Qf [58,66), Kf [66,74), Vt [74,82) (4..5)
    //  [84,..) queue  (4)
    const size_t MB = 1u << 20;
    char* w8 = (char*)d_ws;
    u16*  WOb   = (u16*)(w8 + 0);
    u16*  RqkT  = (u16*)(w8 + 2  * MB);
    u16*  RvT   = (u16*)(w8 + 6  * MB);
    u16*  x_hi  = (u16*)(w8 + 10 * MB);
    u16*  x_lo  = (u16*)(w8 + 18 * MB);
    u16*  FqkTh = (u16*)(w8 + 26 * MB);
    u16*  FqkTl = (u16*)(w8 + 30 * MB);
    u16*  FvT   = (u16*)(w8 + 34 * MB);
    float* h_q  = (float*)(w8 + 42 * MB);
    float* h_k  = (float*)(w8 + 43 * MB);
    float* h_v  = (float*)(w8 + 44 * MB);
    float* P    = (float*)(w8 + 58 * MB);
    u16*  Qf    = (u16*)(w8 + 58 * MB);
    u16*  Kf    = (u16*)(w8 + 66 * MB);
    u16*  Vt    = (u16*)(w8 + 74 * MB);
    u16*  Opart = (u16*)(w8 + 10 * MB);
    float* mlws = (float*)(w8 + 46 * MB);
    u16*  Am    = (u16*)(w8 + 2  * MB);
    int*  queue = (int*)(w8 + 84 * MB);

    dim3 blk(256);

    // casts / transposes (r_qk + r_v merged into one launch)
    cast_split<1><<<dim3(4096), blk, 0, stream>>>(x, x_hi, x_lo, 1024 * 1024);
    cast_split<0><<<dim3(1024), blk, 0, stream>>>(W_O, WOb, nullptr, 256 * 1024);
    transpose_cast<1><<<dim3(2, 32, 32), blk, 0, stream>>>(f_qk, FqkTh, FqkTl, 1024, 64, 1024);
    transpose_cast<0><<<dim3(2, 32, 32), blk, 0, stream>>>(f_v,  FvT,   nullptr, 1024, 64, 1024);
    transpose_cast_h2<<<dim3(32, 64, 2), blk, 0, stream>>>(r_qk, RqkT, r_v, RvT,
                                                           2048, 1024, 2048);

    // projV (bf16 single) + mix -> h_v
    gemm_mfma<0, 2><<<dim3(512), blk, 0, stream>>>(x_hi, nullptr, FvT, nullptr, P,
                                                   4096, 2048, 1024);
    mix_kernel<<<dim3(1024), blk, 0, stream>>>(P, wfv, nullptr, h_v, nullptr, 0);

    // projQK (bf16 split) + mix -> h_q, h_k
    gemm_mfma<1, 2><<<dim3(512), blk, 0, stream>>>(x_hi, x_lo, FqkTh, FqkTl, P,
                                                   4096, 2048, 1024);
    mix_kernel<<<dim3(1024), blk, 0, stream>>>(P, wfqkQ, wfqkK, h_q, h_k, 1);

    // fused restore (fp16, on-the-fly A, BK=64 single-buffer) -> attn operands
    hipMemsetAsync(queue, 0, 8 * sizeof(int), stream);
    restore_mega<<<dim3(768), dim3(512), 0, stream>>>(h_q, wrqkQ, h_k, wrqkK,
                                                      h_v, wrv, RqkT, RvT,
                                                      Qf, Kf, Vt, queue);

    // K-split flash attention (fp16, K/V dbuf): partials + combine
    flash_part<<<dim3(8192), blk, 0, stream>>>(Qf, Kf, Vt, Opart, mlws);
    flash_combine<<<dim3(32, 32), blk, 0, stream>>>(Opart, mlws, Am);

    // output projection (bf16)
    gemm_mfma<0, 1><<<dim3(256), blk, 0, stream>>>(Am, nullptr, WOb, nullptr, out,
                                                   4096, 1024, 1024);
}